// Round 5
// baseline (129.596 us; speedup 1.0000x reference)
//
#include <hip/hip_runtime.h>

// out[n,c,p,y,x] = in1[n,c,y,x] - zpad(in2)[n,c, y+i-3, x+j-3],  p = i*7+j
// N=8, C=32, H=W=112 -> out [8,32,49,112,112] fp32 (629 MB write, 25.7 MB read).
//
// R4: device-wide read/write PHASE SEPARATION. Grid = 256 blocks = 1 per CU,
// block = one nc. Phase 1 (~5 us): in1 plane -> registers (4 f4/thread),
// in2 plane -> LDS (54 KB: 4+112+4 padded pitch, +1 zero row for y-halo).
// Phase 2 (~95 us): pure stores, ZERO global reads device-wide -> no HBM
// read/write turnaround, no L2 input eviction. Each input byte read exactly
// once. Store pattern per wave = 1 KB contiguous full lines (as R3, 128.6 us).
// History: R0 134.7 (scattered, no LDS), R1 172 (plane-block+nt), R2 249
// (plane-block sequential), R3 128.6 (strip LDS staging).

#define HW     112
#define PLANE  12544           // 112*112
#define KK     49
#define NC_TOT 256
#define PITCH  120             // LDS row pitch: 4 zero-pad + 112 data + 4 zero-pad
#define ZROW   112             // all-zero row for out-of-range y
#define LDS_F  ((HW + 1) * PITCH)   // 113*120 = 13560 floats = 54240 B

typedef float f4 __attribute__((ext_vector_type(4)));

__device__ __forceinline__ void process_pos(
    const float* __restrict__ s2, float* __restrict__ o_nc, int e, f4 a)
{
    const int y  = (4 * e) / HW;
    const int x0 = 4 * e - y * HW;
    float* o = o_nc + 4 * e;

    #pragma unroll
    for (int i = 0; i < 7; ++i) {
        const int iy  = y + i - 3;
        const int row = (iy >= 0 && iy < HW) ? iy : ZROW;
        const float* wr = s2 + row * PITCH + x0;   // padded col of x0-4
        const f4 w0 = *reinterpret_cast<const f4*>(wr);
        const f4 w1 = *reinterpret_cast<const f4*>(wr + 4);
        const f4 w2 = *reinterpret_cast<const f4*>(wr + 8);
        float wf[12];
        wf[0]=w0.x; wf[1]=w0.y; wf[2] =w0.z; wf[3] =w0.w;
        wf[4]=w1.x; wf[5]=w1.y; wf[6] =w1.z; wf[7] =w1.w;
        wf[8]=w2.x; wf[9]=w2.y; wf[10]=w2.z; wf[11]=w2.w;
        #pragma unroll
        for (int j = 0; j < 7; ++j) {
            f4 r;
            r.x = a.x - wf[j + 1];
            r.y = a.y - wf[j + 2];
            r.z = a.z - wf[j + 3];
            r.w = a.w - wf[j + 4];
            *reinterpret_cast<f4*>(o + (size_t)(i * 7 + j) * PLANE) = r;
        }
    }
}

__global__ __launch_bounds__(1024) void sub2_kernel(
    const float* __restrict__ in1,
    const float* __restrict__ in2,
    float* __restrict__ out)
{
    __shared__ float s2[LDS_F];

    const int nc = blockIdx.x;          // 0..255, one per CU
    const int t  = threadIdx.x;         // 0..1023

    const float* a_pl = in1 + (size_t)nc * PLANE;
    const float* b_pl = in2 + (size_t)nc * PLANE;
    float*       o_nc = out + (size_t)nc * KK * PLANE;

    // ---- phase 1a: in1 plane -> registers (pos e = t + 1024*k) ----
    const f4 a0 = *reinterpret_cast<const f4*>(a_pl + 4 * t);
    const f4 a1 = *reinterpret_cast<const f4*>(a_pl + 4 * (t + 1024));
    const f4 a2 = *reinterpret_cast<const f4*>(a_pl + 4 * (t + 2048));
    f4 a3 = {0.f, 0.f, 0.f, 0.f};
    if (t < 64) a3 = *reinterpret_cast<const f4*>(a_pl + 4 * (t + 3072));

    // ---- phase 1b: zero LDS, then stage in2 plane ----
    {
        const f4 z = {0.f, 0.f, 0.f, 0.f};
        #pragma unroll
        for (int k = 0; k < 4; ++k) {
            const int s = t + 1024 * k;
            if (s < LDS_F / 4) reinterpret_cast<f4*>(s2)[s] = z;
        }
    }
    __syncthreads();
    #pragma unroll
    for (int k = 0; k < 4; ++k) {
        const int s = t + 1024 * k;          // f4 slot: row r, col c
        if (s < 28 * HW) {
            const int r = s / 28;
            const int c = s - r * 28;
            *reinterpret_cast<f4*>(&s2[r * PITCH + 4 + 4 * c]) =
                *reinterpret_cast<const f4*>(b_pl + r * HW + 4 * c);
        }
    }
    __syncthreads();

    // ---- phase 2: pure stores (49 planes x 3-4 positions/thread) ----
    process_pos(s2, o_nc, t, a0);
    process_pos(s2, o_nc, t + 1024, a1);
    process_pos(s2, o_nc, t + 2048, a2);
    if (t < 64) process_pos(s2, o_nc, t + 3072, a3);
}

extern "C" void kernel_launch(void* const* d_in, const int* in_sizes, int n_in,
                              void* d_out, int out_size, void* d_ws, size_t ws_size,
                              hipStream_t stream) {
    const float* in1 = (const float*)d_in[0];
    const float* in2 = (const float*)d_in[1];
    float* out = (float*)d_out;

    sub2_kernel<<<NC_TOT, 1024, 0, stream>>>(in1, in2, out);
}

// Round 6
// 129.112 us; speedup vs baseline: 1.0037x; 1.0037x over previous
//
#include <hip/hip_runtime.h>

// out[n,c,p,y,x] = in1[n,c,y,x] - zpad(in2)[n,c, y+i-3, x+j-3],  p = i*7+j
// N=8, C=32, H=W=112 -> out [8,32,49,112,112] fp32 (629 MB write, 25.7 MB read).
//
// R5 = R4 (phase-separated, LDS-staged, 1 block/CU) with STORE ORDER swapped
// to plane-major: block writes each 50 KB output plane contiguously before
// moving to the next, instead of every wave hopping across 49 plane streams
// per store (R0/R3/R4 all ~129 us = 4.9 TB/s write vs fill's 6.8 TB/s).
// Device-wide concurrent write streams: ~200K x 1KB  ->  256 x 50KB sweeps.
// History: R0 134.7, R1 172 (nt stores), R2 249 (plane-major but store ILP
// starved by per-store load deps), R3 128.6, R4 129.6.

#define HW     112
#define PLANE  12544           // 112*112
#define KK     49
#define NC_TOT 256
#define PITCH  120             // LDS row pitch: 4 zero-pad + 112 data + 4 zero-pad
#define ZROW   112             // all-zero row for out-of-range y
#define LDS_F  ((HW + 1) * PITCH)   // 113*120 = 13560 floats = 54240 B

typedef float f4 __attribute__((ext_vector_type(4)));

__global__ __launch_bounds__(1024) void sub2_kernel(
    const float* __restrict__ in1,
    const float* __restrict__ in2,
    float* __restrict__ out)
{
    __shared__ float s2[LDS_F];

    const int nc = blockIdx.x;          // 0..255, one per CU
    const int t  = threadIdx.x;         // 0..1023

    const float* a_pl = in1 + (size_t)nc * PLANE;
    const float* b_pl = in2 + (size_t)nc * PLANE;
    float*       o_nc = out + (size_t)nc * KK * PLANE;

    // ---- phase 1a: in1 plane -> registers (position sets e = t + 1024*k) ----
    const f4 a0 = *reinterpret_cast<const f4*>(a_pl + 4 * t);
    const f4 a1 = *reinterpret_cast<const f4*>(a_pl + 4 * (t + 1024));
    const f4 a2 = *reinterpret_cast<const f4*>(a_pl + 4 * (t + 2048));
    f4 a3 = {0.f, 0.f, 0.f, 0.f};
    const bool tail = (t < 64);
    if (tail) a3 = *reinterpret_cast<const f4*>(a_pl + 4 * (t + 3072));

    // ---- phase 1b: zero LDS, then stage in2 plane ----
    {
        const f4 z = {0.f, 0.f, 0.f, 0.f};
        #pragma unroll
        for (int k = 0; k < 4; ++k) {
            const int s = t + 1024 * k;
            if (s < LDS_F / 4) reinterpret_cast<f4*>(s2)[s] = z;
        }
    }
    __syncthreads();
    #pragma unroll
    for (int k = 0; k < 4; ++k) {
        const int s = t + 1024 * k;          // f4 slot: row r, col c
        if (s < 28 * HW) {
            const int r = s / 28;
            const int c = s - r * 28;
            *reinterpret_cast<f4*>(&s2[r * PITCH + 4 + 4 * c]) =
                *reinterpret_cast<const f4*>(b_pl + r * HW + 4 * c);
        }
    }
    __syncthreads();

    // position decode per set (e_k = t + 1024k, float index 4*e_k)
    int yk[4], xk[4];
    #pragma unroll
    for (int k = 0; k < 4; ++k) {
        const int e = t + 1024 * k;
        yk[k] = (4 * e) / HW;
        xk[k] = 4 * e - yk[k] * HW;
    }

    float* const ob0 = o_nc + 4 * (size_t)t;
    float* const ob1 = o_nc + 4 * (size_t)(t + 1024);
    float* const ob2 = o_nc + 4 * (size_t)(t + 2048);
    float* const ob3 = o_nc + 4 * (size_t)(t + 3072);

    // ---- phase 2: plane-major stores ----
    #pragma unroll
    for (int i = 0; i < 7; ++i) {
        // window wf[k][m] = in2 value at x-coord xk-4+m, row yk+i-3 (clamped)
        float wf0[12], wf1[12], wf2[12], wf3[12];
        {
            #pragma unroll
            for (int k = 0; k < 3; ++k) {
                const int iy  = yk[k] + i - 3;
                const int row = ((unsigned)iy < HW) ? iy : ZROW;
                const float* wr = s2 + row * PITCH + xk[k];  // = padded x0-4
                const f4 w0 = *reinterpret_cast<const f4*>(wr);
                const f4 w1 = *reinterpret_cast<const f4*>(wr + 4);
                const f4 w2 = *reinterpret_cast<const f4*>(wr + 8);
                float* wf = (k == 0) ? wf0 : (k == 1) ? wf1 : wf2;
                wf[0]=w0.x; wf[1]=w0.y; wf[2] =w0.z; wf[3] =w0.w;
                wf[4]=w1.x; wf[5]=w1.y; wf[6] =w1.z; wf[7] =w1.w;
                wf[8]=w2.x; wf[9]=w2.y; wf[10]=w2.z; wf[11]=w2.w;
            }
            if (tail) {
                const int iy  = yk[3] + i - 3;
                const int row = ((unsigned)iy < HW) ? iy : ZROW;
                const float* wr = s2 + row * PITCH + xk[3];
                const f4 w0 = *reinterpret_cast<const f4*>(wr);
                const f4 w1 = *reinterpret_cast<const f4*>(wr + 4);
                const f4 w2 = *reinterpret_cast<const f4*>(wr + 8);
                wf3[0]=w0.x; wf3[1]=w0.y; wf3[2] =w0.z; wf3[3] =w0.w;
                wf3[4]=w1.x; wf3[5]=w1.y; wf3[6] =w1.z; wf3[7] =w1.w;
                wf3[8]=w2.x; wf3[9]=w2.y; wf3[10]=w2.z; wf3[11]=w2.w;
            }
        }

        #pragma unroll
        for (int j = 0; j < 7; ++j) {
            const size_t po = (size_t)(i * 7 + j) * PLANE;
            f4 r;
            r.x = a0.x - wf0[j + 1];
            r.y = a0.y - wf0[j + 2];
            r.z = a0.z - wf0[j + 3];
            r.w = a0.w - wf0[j + 4];
            *reinterpret_cast<f4*>(ob0 + po) = r;
            r.x = a1.x - wf1[j + 1];
            r.y = a1.y - wf1[j + 2];
            r.z = a1.z - wf1[j + 3];
            r.w = a1.w - wf1[j + 4];
            *reinterpret_cast<f4*>(ob1 + po) = r;
            r.x = a2.x - wf2[j + 1];
            r.y = a2.y - wf2[j + 2];
            r.z = a2.z - wf2[j + 3];
            r.w = a2.w - wf2[j + 4];
            *reinterpret_cast<f4*>(ob2 + po) = r;
            if (tail) {
                r.x = a3.x - wf3[j + 1];
                r.y = a3.y - wf3[j + 2];
                r.z = a3.z - wf3[j + 3];
                r.w = a3.w - wf3[j + 4];
                *reinterpret_cast<f4*>(ob3 + po) = r;
            }
        }
    }
}

extern "C" void kernel_launch(void* const* d_in, const int* in_sizes, int n_in,
                              void* d_out, int out_size, void* d_ws, size_t ws_size,
                              hipStream_t stream) {
    const float* in1 = (const float*)d_in[0];
    const float* in2 = (const float*)d_in[1];
    float* out = (float*)d_out;

    sub2_kernel<<<NC_TOT, 1024, 0, stream>>>(in1, in2, out);
}